// Round 16
// baseline (48942.169 us; speedup 1.0000x reference)
//
#include <hip/hip_runtime.h>
#include <math.h>

// VanillaRNN B=256,T=512,H=1024,O=10 — bit-exact replication of reference CPU
// fp32 trajectory. Decoded arithmetic (R5-R7 oracle): kc=512 panels, no-FMA
// chains (__fmul_rn/__fadd_rn, k ascending, panels joined in order), tanh =
// clamp ±7.99881172180175781 + fmaf Horner + IEEE div, no-FMA xp.
//
// R16 = R14 resource profile + 2 waves/SIMD at FULL per-thread intensity:
// 512 thr, 1 WG/CU; waves 0-3 = panel0 (LDS W, 128 KB) for rows w*4..w*4+3,
// waves 4-7 = panel1 (global W) same rows; thread = 4 rows x 1 col x 1 panel
// (4 chains x 512 MACC — R14's ratio, R14's total vmem count). SIMD pairs
// (w, w+4) are complementary LDS-fed/global-fed. Join: panel0 partials via
// 4 KB LDS + 1 barrier; panel1 wave does m=fadd(p0,p1), xp, tanh, store.
// Sync / XCD-local mapping / epilogue: R14 verbatim.

#define HH 1024
#define TT 512
#define BB 256
#define OO 10
#define NG 16      // row groups (16 rows)
#define NCT 16     // col tiles (64 cols)
#define NTH 512
#define KH 512     // panel size

__device__ __forceinline__ float tanh_ref(float x) {
    const float kClamp = 7.99881172180175781f;
    float xc = fminf(fmaxf(x, -kClamp), kClamp);
    float x2 = __fmul_rn(xc, xc);
    float p = -2.76076847742355e-16f;
    p = fmaf(x2, p,  2.00018790482477e-13f);
    p = fmaf(x2, p, -8.60467152213735e-11f);
    p = fmaf(x2, p,  5.12229709037114e-08f);
    p = fmaf(x2, p,  1.48572235717979e-05f);
    p = fmaf(x2, p,  6.37261928875436e-04f);
    p = fmaf(x2, p,  4.89352455891786e-03f);
    p = __fmul_rn(xc, p);
    float q = 1.19825839466702e-06f;
    q = fmaf(x2, q, 1.18534705686654e-04f);
    q = fmaf(x2, q, 2.26843463243900e-03f);
    q = fmaf(x2, q, 4.89352518554385e-03f);
    float r = __fdiv_rn(p, q);
    return (fabsf(x) < 0.0004f) ? x : r;
}

#define MACC(acc, hv, wv) acc = __fadd_rn(acc, __fmul_rn(hv, wv))

__global__ void __launch_bounds__(NTH, 1) rnn_persist(
    const float* __restrict__ x, const float* __restrict__ Whx,
    const float* __restrict__ Whh, const float* __restrict__ Wph,
    const float* __restrict__ bh, const float* __restrict__ bo,
    float* __restrict__ out, float* __restrict__ ws)
{
    __shared__ float wlds[KH][64];      // 128 KB: W[k<512][j0..j0+64)
    __shared__ float part[4][4][64];    // 4 KB: panel0 partials [wavepair][row][lane]

    const int bid  = blockIdx.x;        // 0..255
    const int ct   = (bid >> 3) & 15;                 // col tile
    const int g    = ((bid & 7) << 1) | (bid >> 7);   // row group; bid%8 == g>>1
    const int tid  = threadIdx.x;
    const int w    = tid >> 6;          // wave 0..7
    const int lane = tid & 63;
    const int wp4  = w & 3;             // wave-pair index 0..3
    const int isP1 = w >> 2;            // 0 = panel0 wave, 1 = panel1 wave
    const int j0   = ct * 64;
    const int j    = j0 + lane;         // this thread's column
    const int r0w  = g * 16 + wp4 * 4;  // this thread's 4 rows

    float* hAbuf = ws;                  // [256][1024]
    float* hBbuf = ws + (BB * HH);
    int*   ctr   = (int*)(ws + 2 * BB * HH);  // [16], memset 0 pre-launch

    const float whx_j = Whx[j];
    const float bh_j  = bh[j];

    // ---- one-time W panel0 preload: 8192 float4 slots, coalesced ----
    #pragma unroll
    for (int i = 0; i < 16; ++i) {
        const int s = tid + i * NTH;     // 0..8191
        const int k = s >> 4;            // 0..511
        const int c = s & 15;            // float4 within 64-col row
        ((float4*)wlds)[s] = ((const float4*)(Whh + (size_t)k * HH + j0))[c];
    }

    // ---- zero-init hA rows (panel0 waves), then group sync (R14 verbatim) ----
    if (!isP1) {
        #pragma unroll
        for (int r = 0; r < 4; ++r)
            hAbuf[(size_t)(r0w + r) * HH + j] = 0.0f;
    }
    __threadfence();
    __syncthreads();
    if (tid == 0) {
        __hip_atomic_fetch_add(&ctr[g], 1, __ATOMIC_RELEASE, __HIP_MEMORY_SCOPE_AGENT);
        while (__hip_atomic_load(&ctr[g], __ATOMIC_ACQUIRE, __HIP_MEMORY_SCOPE_AGENT) < NCT)
            __builtin_amdgcn_s_sleep(2);
    }
    __syncthreads();
    __threadfence();

    for (int t = 0; t < TT; ++t) {
        const float* hsrc = (t & 1) ? hBbuf : hAbuf;
        float*       hdst = (t & 1) ? hAbuf : hBbuf;

        float a0 = 0.f, a1 = 0.f, a2 = 0.f, a3 = 0.f;

        if (!isP1) {
            // ---- panel0: k = 0..511, W from LDS, h from global ----
            const float* h0p = hsrc + (size_t)(r0w + 0) * HH;
            const float* h1p = hsrc + (size_t)(r0w + 1) * HH;
            const float* h2p = hsrc + (size_t)(r0w + 2) * HH;
            const float* h3p = hsrc + (size_t)(r0w + 3) * HH;
            #pragma unroll 4
            for (int k4 = 0; k4 < KH; k4 += 4) {
                const float4 h0 = *(const float4*)(h0p + k4);
                const float4 h1 = *(const float4*)(h1p + k4);
                const float4 h2 = *(const float4*)(h2p + k4);
                const float4 h3 = *(const float4*)(h3p + k4);
                const float w0 = wlds[k4 + 0][lane];
                const float w1 = wlds[k4 + 1][lane];
                const float w2 = wlds[k4 + 2][lane];
                const float w3 = wlds[k4 + 3][lane];
                // k ascending — chain order is the correctness contract
                MACC(a0, h0.x, w0); MACC(a1, h1.x, w0); MACC(a2, h2.x, w0); MACC(a3, h3.x, w0);
                MACC(a0, h0.y, w1); MACC(a1, h1.y, w1); MACC(a2, h2.y, w1); MACC(a3, h3.y, w1);
                MACC(a0, h0.z, w2); MACC(a1, h1.z, w2); MACC(a2, h2.z, w2); MACC(a3, h3.z, w2);
                MACC(a0, h0.w, w3); MACC(a1, h1.w, w3); MACC(a2, h2.w, w3); MACC(a3, h3.w, w3);
            }
            part[wp4][0][lane] = a0;
            part[wp4][1][lane] = a1;
            part[wp4][2][lane] = a2;
            part[wp4][3][lane] = a3;
        } else {
            // ---- panel1: k = 512..1023, W + h from global ----
            const float* h0p = hsrc + (size_t)(r0w + 0) * HH + KH;
            const float* h1p = hsrc + (size_t)(r0w + 1) * HH + KH;
            const float* h2p = hsrc + (size_t)(r0w + 2) * HH + KH;
            const float* h3p = hsrc + (size_t)(r0w + 3) * HH + KH;
            const float* wgp = Whh + (size_t)KH * HH + j;
            #pragma unroll 4
            for (int k4 = 0; k4 < KH; k4 += 4) {
                const float4 h0 = *(const float4*)(h0p + k4);
                const float4 h1 = *(const float4*)(h1p + k4);
                const float4 h2 = *(const float4*)(h2p + k4);
                const float4 h3 = *(const float4*)(h3p + k4);
                const float v0 = wgp[0];
                const float v1 = wgp[HH];
                const float v2 = wgp[2 * HH];
                const float v3 = wgp[3 * HH];
                wgp += 4 * HH;
                MACC(a0, h0.x, v0); MACC(a1, h1.x, v0); MACC(a2, h2.x, v0); MACC(a3, h3.x, v0);
                MACC(a0, h0.y, v1); MACC(a1, h1.y, v1); MACC(a2, h2.y, v1); MACC(a3, h3.y, v1);
                MACC(a0, h0.z, v2); MACC(a1, h1.z, v2); MACC(a2, h2.z, v2); MACC(a3, h3.z, v2);
                MACC(a0, h0.w, v3); MACC(a1, h1.w, v3); MACC(a2, h2.w, v3); MACC(a3, h3.w, v3);
            }
        }

        __syncthreads();   // panel0 partials visible

        if (isP1) {
            // join (p0 then p1), xp, z, tanh, store — contract order
            const float m0 = __fadd_rn(part[wp4][0][lane], a0);
            const float m1 = __fadd_rn(part[wp4][1][lane], a1);
            const float m2 = __fadd_rn(part[wp4][2][lane], a2);
            const float m3 = __fadd_rn(part[wp4][3][lane], a3);
            const float xv0 = x[(r0w + 0) * TT + t];
            const float xv1 = x[(r0w + 1) * TT + t];
            const float xv2 = x[(r0w + 2) * TT + t];
            const float xv3 = x[(r0w + 3) * TT + t];
            hdst[(size_t)(r0w + 0) * HH + j] =
                tanh_ref(__fadd_rn(__fadd_rn(__fmul_rn(xv0, whx_j), bh_j), m0));
            hdst[(size_t)(r0w + 1) * HH + j] =
                tanh_ref(__fadd_rn(__fadd_rn(__fmul_rn(xv1, whx_j), bh_j), m1));
            hdst[(size_t)(r0w + 2) * HH + j] =
                tanh_ref(__fadd_rn(__fadd_rn(__fmul_rn(xv2, whx_j), bh_j), m2));
            hdst[(size_t)(r0w + 3) * HH + j] =
                tanh_ref(__fadd_rn(__fadd_rn(__fmul_rn(xv3, whx_j), bh_j), m3));
        }

        // row-group sync (monotonic counter, agent scope — R14 verbatim)
        __threadfence();
        __syncthreads();
        if (tid == 0) {
            __hip_atomic_fetch_add(&ctr[g], 1, __ATOMIC_RELEASE, __HIP_MEMORY_SCOPE_AGENT);
            const int target = NCT * (t + 2);
            while (__hip_atomic_load(&ctr[g], __ATOMIC_ACQUIRE, __HIP_MEMORY_SCOPE_AGENT) < target)
                __builtin_amdgcn_s_sleep(2);
        }
        __syncthreads();
        __threadfence();
    }

    // ---- epilogue: out = h_final @ Wph + bo (h_final in hAbuf; TT even) ----
    if (ct == 0) {
        #pragma unroll 1
        for (int p = w; p < 16 * OO; p += 8) {
            const int rr = p / OO, o = p % OO;
            const int row = g * 16 + rr;
            float v = 0.0f;
            #pragma unroll
            for (int m = 0; m < HH / 64; ++m) {
                const int k = lane + (m << 6);
                v = fmaf(hAbuf[(size_t)row * HH + k], Wph[k * OO + o], v);
            }
            #pragma unroll
            for (int s = 32; s > 0; s >>= 1) v += __shfl_down(v, s, 64);
            if (lane == 0) out[row * OO + o] = v + bo[o];
        }
    }
}

extern "C" void kernel_launch(void* const* d_in, const int* in_sizes, int n_in,
                              void* d_out, int out_size, void* d_ws, size_t ws_size,
                              hipStream_t stream) {
    const float* x   = (const float*)d_in[0];
    const float* Whx = (const float*)d_in[1];
    const float* Whh = (const float*)d_in[2];
    const float* Wph = (const float*)d_in[3];
    const float* bh  = (const float*)d_in[4];
    const float* bo  = (const float*)d_in[5];
    float* out = (float*)d_out;
    float* ws  = (float*)d_ws;

    // reset row-group counters (R14 verbatim region, 64 B at 2 MB offset)
    hipMemsetAsync((char*)d_ws + (size_t)2 * BB * HH * 4, 0, NG * sizeof(int), stream);

    void* args[] = {(void*)&x, (void*)&Whx, (void*)&Whh, (void*)&Wph,
                    (void*)&bh, (void*)&bo, (void*)&out, (void*)&ws};
    hipLaunchCooperativeKernel((void*)rnn_persist, dim3(NG * NCT), dim3(NTH),
                               args, 0, stream);
}

// Round 17
// 18607.962 us; speedup vs baseline: 2.6302x; 2.6302x over previous
//
#include <hip/hip_runtime.h>
#include <math.h>

// VanillaRNN B=256,T=512,H=1024,O=10 — bit-exact replication of reference CPU
// fp32 trajectory. Decoded arithmetic (R5-R7 oracle): kc=512 panels, no-FMA
// chains (__fmul_rn/__fadd_rn, k ascending, panels joined in order), tanh =
// clamp ±7.99881172180175781 + fmaf Horner + IEEE div, no-FMA xp.
//
// R17 = R14 body VERBATIM + de-poisoned group sync (single variable).
// R16 post-mortem: FETCH_SIZE ~92-109 MB/dispatch => W refetched ~25x. The
// ACQUIRE agent atomic in the spin loop emits buffer_inv sc1 (full per-XCD L2
// invalidate) EVERY POLL; __threadfence() adds buffer_wbl2 sc1. Our own sync
// was flushing the XCD's L2 ~continuously -> every k-loop load became an
// L3 round-trip at 1 wave/SIMD. Fix (groups are XCD-local by construction,
// bid%8 invariant, de-facto placement in all passing rounds R8-R16):
//   producer release = __syncthreads() (drains vmcnt(0); stores reach L2)
//   counter          = RELAXED agent atomics (coherence point, no cache ops)
//   consumer acquire = one plain buffer_inv (vL1-only, cheap) after spin
// No L2 writeback/invalidate anywhere in the 512-step loop.

#define HH 1024
#define TT 512
#define BB 256
#define OO 10
#define NG 16      // row groups (16 rows)
#define NCT 16     // col tiles (64 cols)
#define NTH 256
#define KH 512     // panel size

__device__ __forceinline__ float tanh_ref(float x) {
    const float kClamp = 7.99881172180175781f;
    float xc = fminf(fmaxf(x, -kClamp), kClamp);
    float x2 = __fmul_rn(xc, xc);
    float p = -2.76076847742355e-16f;
    p = fmaf(x2, p,  2.00018790482477e-13f);
    p = fmaf(x2, p, -8.60467152213735e-11f);
    p = fmaf(x2, p,  5.12229709037114e-08f);
    p = fmaf(x2, p,  1.48572235717979e-05f);
    p = fmaf(x2, p,  6.37261928875436e-04f);
    p = fmaf(x2, p,  4.89352455891786e-03f);
    p = __fmul_rn(xc, p);
    float q = 1.19825839466702e-06f;
    q = fmaf(x2, q, 1.18534705686654e-04f);
    q = fmaf(x2, q, 2.26843463243900e-03f);
    q = fmaf(x2, q, 4.89352518554385e-03f);
    float r = __fdiv_rn(p, q);
    return (fabsf(x) < 0.0004f) ? x : r;
}

#define MACC(acc, hv, wv) acc = __fadd_rn(acc, __fmul_rn(hv, wv))

// De-poisoned row-group sync. Requires: producer stores drained to L2
// (__syncthreads does vmcnt(0)); group XCD-local (L2 = common point);
// consumer L1 invalidated before reading h (plain buffer_inv = vL1 only).
#define GROUPSYNC_FAST(target_) {                                                   \
    __syncthreads();  /* all h-stores of this WG at L2 */                            \
    if (tid == 0) {                                                                  \
        __hip_atomic_fetch_add(&ctr[g], 1, __ATOMIC_RELAXED, __HIP_MEMORY_SCOPE_AGENT); \
        while (__hip_atomic_load(&ctr[g], __ATOMIC_RELAXED, __HIP_MEMORY_SCOPE_AGENT)   \
               < (target_))                                                          \
            __builtin_amdgcn_s_sleep(2);                                             \
    }                                                                                \
    __syncthreads();                                                                 \
    asm volatile("buffer_inv" ::: "memory");  /* vL1 invalidate, no L2 touch */      \
}

__global__ void __launch_bounds__(NTH, 1) rnn_persist(
    const float* __restrict__ x, const float* __restrict__ Whx,
    const float* __restrict__ Whh, const float* __restrict__ Wph,
    const float* __restrict__ bh, const float* __restrict__ bo,
    float* __restrict__ out, float* __restrict__ ws)
{
    __shared__ float wlds[KH][64];      // 128 KB: W[k<512][j0..j0+64)

    const int bid  = blockIdx.x;        // 0..255
    const int ct   = (bid >> 3) & 15;                 // col tile
    const int g    = ((bid & 7) << 1) | (bid >> 7);   // row group; bid%8 == g>>1
    const int tid  = threadIdx.x;
    const int w    = tid >> 6;          // wave 0..3
    const int lane = tid & 63;
    const int j0   = ct * 64;
    const int j    = j0 + lane;         // this thread's column
    const int r0w  = g * 16 + w * 4;    // this wave's first row

    float* hAbuf = ws;                  // [256][1024]
    float* hBbuf = ws + (BB * HH);
    int*   ctr   = (int*)(ws + 2 * BB * HH);  // [16], memset 0 pre-launch

    const float whx_j = Whx[j];
    const float bh_j  = bh[j];

    // ---- one-time W panel0 preload: 8192 float4 slots, coalesced ----
    #pragma unroll
    for (int i = 0; i < 32; ++i) {
        const int s = tid + i * NTH;     // 0..8191
        const int k = s >> 4;            // 0..511
        const int c = s & 15;            // float4 within 64-col row
        ((float4*)wlds)[s] = ((const float4*)(Whh + (size_t)k * HH + j0))[c];
    }

    // ---- zero-init hA rows, then group sync ----
    #pragma unroll
    for (int r = 0; r < 4; ++r)
        hAbuf[(size_t)(r0w + r) * HH + j] = 0.0f;
    GROUPSYNC_FAST(NCT)

    for (int t = 0; t < TT; ++t) {
        const float* hsrc = (t & 1) ? hBbuf : hAbuf;
        float*       hdst = (t & 1) ? hAbuf : hBbuf;

        const float* h0p = hsrc + (size_t)(r0w + 0) * HH;
        const float* h1p = hsrc + (size_t)(r0w + 1) * HH;
        const float* h2p = hsrc + (size_t)(r0w + 2) * HH;
        const float* h3p = hsrc + (size_t)(r0w + 3) * HH;
        const float* wp1 = Whh + (size_t)KH * HH + j;   // panel1 W[512+k][j]

        float a0 = 0.f, a1 = 0.f, a2 = 0.f, a3 = 0.f;   // panel0 chains
        float b0 = 0.f, b1 = 0.f, b2 = 0.f, b3 = 0.f;   // panel1 chains

        #pragma unroll 2
        for (int k4 = 0; k4 < KH; k4 += 4) {
            // h for both panels, wave-uniform float4 broadcasts
            const float4 ha0 = *(const float4*)(h0p + k4);
            const float4 ha1 = *(const float4*)(h1p + k4);
            const float4 ha2 = *(const float4*)(h2p + k4);
            const float4 ha3 = *(const float4*)(h3p + k4);
            const float4 hb0 = *(const float4*)(h0p + KH + k4);
            const float4 hb1 = *(const float4*)(h1p + KH + k4);
            const float4 hb2 = *(const float4*)(h2p + KH + k4);
            const float4 hb3 = *(const float4*)(h3p + KH + k4);
            // panel0 W from LDS (2-way aliasing = free)
            const float w0 = wlds[k4 + 0][lane];
            const float w1 = wlds[k4 + 1][lane];
            const float w2 = wlds[k4 + 2][lane];
            const float w3 = wlds[k4 + 3][lane];
            // panel1 W from global (coalesced 256B per k-row)
            const float v0 = wp1[0];
            const float v1 = wp1[HH];
            const float v2 = wp1[2 * HH];
            const float v3 = wp1[3 * HH];
            wp1 += 4 * HH;
            // k ascending per panel — chain order is the correctness contract
            MACC(a0, ha0.x, w0); MACC(a1, ha1.x, w0); MACC(a2, ha2.x, w0); MACC(a3, ha3.x, w0);
            MACC(b0, hb0.x, v0); MACC(b1, hb1.x, v0); MACC(b2, hb2.x, v0); MACC(b3, hb3.x, v0);
            MACC(a0, ha0.y, w1); MACC(a1, ha1.y, w1); MACC(a2, ha2.y, w1); MACC(a3, ha3.y, w1);
            MACC(b0, hb0.y, v1); MACC(b1, hb1.y, v1); MACC(b2, hb2.y, v1); MACC(b3, hb3.y, v1);
            MACC(a0, ha0.z, w2); MACC(a1, ha1.z, w2); MACC(a2, ha2.z, w2); MACC(a3, ha3.z, w2);
            MACC(b0, hb0.z, v2); MACC(b1, hb1.z, v2); MACC(b2, hb2.z, v2); MACC(b3, hb3.z, v2);
            MACC(a0, ha0.w, w3); MACC(a1, ha1.w, w3); MACC(a2, ha2.w, w3); MACC(a3, ha3.w, w3);
            MACC(b0, hb0.w, v3); MACC(b1, hb1.w, v3); MACC(b2, hb2.w, v3); MACC(b3, hb3.w, v3);
        }

        // join panels (p0 then p1), xp, z, tanh, store (contract order)
        {
            const float m0 = __fadd_rn(a0, b0);
            const float m1 = __fadd_rn(a1, b1);
            const float m2 = __fadd_rn(a2, b2);
            const float m3 = __fadd_rn(a3, b3);
            const float xv0 = x[(r0w + 0) * TT + t];
            const float xv1 = x[(r0w + 1) * TT + t];
            const float xv2 = x[(r0w + 2) * TT + t];
            const float xv3 = x[(r0w + 3) * TT + t];
            hdst[(size_t)(r0w + 0) * HH + j] =
                tanh_ref(__fadd_rn(__fadd_rn(__fmul_rn(xv0, whx_j), bh_j), m0));
            hdst[(size_t)(r0w + 1) * HH + j] =
                tanh_ref(__fadd_rn(__fadd_rn(__fmul_rn(xv1, whx_j), bh_j), m1));
            hdst[(size_t)(r0w + 2) * HH + j] =
                tanh_ref(__fadd_rn(__fadd_rn(__fmul_rn(xv2, whx_j), bh_j), m2));
            hdst[(size_t)(r0w + 3) * HH + j] =
                tanh_ref(__fadd_rn(__fadd_rn(__fmul_rn(xv3, whx_j), bh_j), m3));
        }

        GROUPSYNC_FAST(NCT * (t + 2))
    }

    // ---- epilogue: out = h_final @ Wph + bo (h_final in hAbuf; TT even) ----
    if (ct == 0) {
        #pragma unroll 1
        for (int r = 0; r < 4; ++r) {
            const int row = r0w + r;
            #pragma unroll 1
            for (int o = 0; o < OO; ++o) {
                float v = 0.0f;
                #pragma unroll
                for (int m = 0; m < HH / 64; ++m) {
                    const int k = lane + (m << 6);
                    v = fmaf(hAbuf[(size_t)row * HH + k], Wph[k * OO + o], v);
                }
                #pragma unroll
                for (int s = 32; s > 0; s >>= 1) v += __shfl_down(v, s, 64);
                if (lane == 0) out[row * OO + o] = v + bo[o];
            }
        }
    }
}

extern "C" void kernel_launch(void* const* d_in, const int* in_sizes, int n_in,
                              void* d_out, int out_size, void* d_ws, size_t ws_size,
                              hipStream_t stream) {
    const float* x   = (const float*)d_in[0];
    const float* Whx = (const float*)d_in[1];
    const float* Whh = (const float*)d_in[2];
    const float* Wph = (const float*)d_in[3];
    const float* bh  = (const float*)d_in[4];
    const float* bo  = (const float*)d_in[5];
    float* out = (float*)d_out;
    float* ws  = (float*)d_ws;

    // reset row-group counters (R14 verbatim region, 64 B at 2 MB offset)
    hipMemsetAsync((char*)d_ws + (size_t)2 * BB * HH * 4, 0, NG * sizeof(int), stream);

    void* args[] = {(void*)&x, (void*)&Whx, (void*)&Whh, (void*)&Wph,
                    (void*)&bh, (void*)&bo, (void*)&out, (void*)&ws};
    hipLaunchCooperativeKernel((void*)rnn_persist, dim3(NG * NCT), dim3(NTH),
                               args, 0, stream);
}